// Round 1
// 1848.724 us; speedup vs baseline: 1.1097x; 1.1097x over previous
//
#include <hip/hip_runtime.h>

#define NN 100000      // nodes in subgraph
#define EE 1000000     // edges
#define BB 20000       // batch size
#define NB 100352      // histogram bins, padded to 98*1024
#define NCH 98         // scan chunks of 1024
// dims: MEM=128, EMB=128, TD=64, MSG=64, HID=128, OUT=64, H=2, D=64

// ---------------------------------------------------------------------------
// Counting-sort of edges by dst: hist -> chunk sums -> chunk scan -> bin scan
// -> scatter perm. bins becomes the running cursor after k_bscan.
// ---------------------------------------------------------------------------
__global__ __launch_bounds__(256) void k_hist(
    const int* __restrict__ eidx, int* __restrict__ bins)
{
    int e = blockIdx.x * 256 + threadIdx.x;
    if (e < EE) atomicAdd(&bins[eidx[EE + e]], 1);
}

__global__ __launch_bounds__(256) void k_csum(
    const int* __restrict__ bins, int* __restrict__ csum)
{
    __shared__ int s[256];
    int tid = threadIdx.x;
    int i0 = blockIdx.x * 1024 + tid * 4;
    s[tid] = bins[i0] + bins[i0+1] + bins[i0+2] + bins[i0+3];
    __syncthreads();
    for (int off = 128; off > 0; off >>= 1) {
        if (tid < off) s[tid] += s[tid + off];
        __syncthreads();
    }
    if (tid == 0) csum[blockIdx.x] = s[0];
}

__global__ __launch_bounds__(128) void k_cscan(
    const int* __restrict__ csum, int* __restrict__ cbase)
{
    __shared__ int s[128];
    int tid = threadIdx.x;
    s[tid] = (tid < NCH) ? csum[tid] : 0;
    __syncthreads();
    for (int off = 1; off < 128; off <<= 1) {
        int t = (tid >= off) ? s[tid - off] : 0;
        __syncthreads();
        s[tid] += t;
        __syncthreads();
    }
    if (tid < NCH) cbase[tid] = tid ? s[tid - 1] : 0;
}

__global__ __launch_bounds__(256) void k_bscan(
    int* __restrict__ bins, const int* __restrict__ cbase)
{
    __shared__ int s[256];
    int tid = threadIdx.x;
    int i0 = blockIdx.x * 1024 + tid * 4;
    int v0 = bins[i0], v1 = bins[i0+1], v2 = bins[i0+2], v3 = bins[i0+3];
    int p0 = v0, p1 = p0 + v1, p2 = p1 + v2, p3 = p2 + v3;
    s[tid] = p3;
    __syncthreads();
    for (int off = 1; off < 256; off <<= 1) {
        int t = (tid >= off) ? s[tid - off] : 0;
        __syncthreads();
        s[tid] += t;
        __syncthreads();
    }
    int base = cbase[blockIdx.x] + (tid ? s[tid - 1] : 0);
    bins[i0]   = base;
    bins[i0+1] = base + p0;
    bins[i0+2] = base + p1;
    bins[i0+3] = base + p2;
}

__global__ __launch_bounds__(256) void k_scatter(
    const int* __restrict__ eidx, int* __restrict__ bins, int* __restrict__ perm)
{
    int e = blockIdx.x * 256 + threadIdx.x;
    if (e < EE) {
        int d = eidx[EE + e];
        int pos = atomicAdd(&bins[d], 1);
        perm[pos] = e;
    }
}

// ---------------------------------------------------------------------------
// q,k,v,skip = (memory_table[n_id] @ {Wq,Wk,Wv,Wskip}) + bias ; lu gather.
// A tile (64 rows x 128) staged ONCE in LDS, then 8 passes (4 weights x 2
// column halves).
// ---------------------------------------------------------------------------
__global__ __launch_bounds__(256) void k_node(
    const float* __restrict__ memt, const float* __restrict__ lut,
    const int* __restrict__ n_id,
    const float* __restrict__ Wq, const float* __restrict__ bq,
    const float* __restrict__ Wk, const float* __restrict__ bk,
    const float* __restrict__ Wv, const float* __restrict__ bv,
    const float* __restrict__ Wsk, const float* __restrict__ bsk,
    float* __restrict__ q, float* __restrict__ k, float* __restrict__ v,
    float* __restrict__ skip, float* __restrict__ lu)
{
    __shared__ float As[128][68];   // A^T: [kdim][row], 16B-aligned rows
    __shared__ float Bs[32][68];
    __shared__ int nid_s[64];
    const int tid = threadIdx.x;
    const int r0 = blockIdx.x * 64;

    if (tid < 64) {
        int r = r0 + tid;
        int id = (r < NN) ? n_id[r] : 0;
        nid_s[tid] = id;
        if (r < NN) lu[r] = lut[id];
    }
    __syncthreads();
    #pragma unroll
    for (int i = 0; i < 8; ++i) {                // A: 64 rows x 128 k, once
        int idx = i*256 + tid;
        int r = idx >> 5, c4 = idx & 31;
        float4 a = *(const float4*)&memt[(size_t)nid_s[r]*128 + c4*4];
        As[c4*4+0][r] = a.x; As[c4*4+1][r] = a.y;
        As[c4*4+2][r] = a.z; As[c4*4+3][r] = a.w;
    }

    const int ty = tid >> 4, tx = tid & 15;
    #pragma unroll 1
    for (int pass = 0; pass < 8; ++pass) {
        const int wsel = pass >> 1, half = pass & 1;
        const float* W    = wsel==0?Wq : wsel==1?Wk : wsel==2?Wv : Wsk;
        const float* bias = wsel==0?bq : wsel==1?bk : wsel==2?bv : bsk;
        float* outp       = wsel==0?q  : wsel==1?k  : wsel==2?v  : skip;
        float acc[4][4] = {};
        #pragma unroll 1
        for (int kt = 0; kt < 4; ++kt) {
            __syncthreads();   // also covers As-load completion on first pass
            #pragma unroll
            for (int i = 0; i < 2; ++i) {        // B: 32 k x 64 cols
                int idx = i*256 + tid;
                int kk = idx >> 4, c4 = idx & 15;
                *(float4*)&Bs[kk][c4*4] =
                    *(const float4*)&W[(size_t)(kt*32+kk)*128 + half*64 + c4*4];
            }
            __syncthreads();
            #pragma unroll
            for (int kk = 0; kk < 32; ++kk) {
                float4 a = *(const float4*)&As[kt*32+kk][ty*4];
                float4 b = *(const float4*)&Bs[kk][tx*4];
                float av[4] = {a.x,a.y,a.z,a.w};
                float bw[4] = {b.x,b.y,b.z,b.w};
                #pragma unroll
                for (int ii = 0; ii < 4; ++ii)
                    #pragma unroll
                    for (int jj = 0; jj < 4; ++jj)
                        acc[ii][jj] = fmaf(av[ii], bw[jj], acc[ii][jj]);
            }
        }
        float4 bia = *(const float4*)&bias[half*64 + tx*4];
        float bw[4] = {bia.x,bia.y,bia.z,bia.w};
        #pragma unroll
        for (int ii = 0; ii < 4; ++ii) {
            int r = r0 + ty*4 + ii;
            if (r < NN) {
                float4 o = make_float4(acc[ii][0]+bw[0], acc[ii][1]+bw[1],
                                       acc[ii][2]+bw[2], acc[ii][3]+bw[3]);
                *(float4*)&outp[(size_t)r*128 + half*64 + tx*4] = o;
            }
        }
    }
}

// ---------------------------------------------------------------------------
// qe[n, h*128 + j] = sum_d q[n, h*64+d] * We[j, h*64+d]
// (per-node pre-projection so per-edge logits need only edge_attr . qe[dst])
// grid (1563, 2) — blockIdx.y = head
// ---------------------------------------------------------------------------
__global__ __launch_bounds__(256) void k_qe(
    const float* __restrict__ q, const float* __restrict__ We,
    float* __restrict__ qe)
{
    __shared__ float As[64][68];    // A^T: [d][row]
    __shared__ float Bs[32][132];   // B:   [d-slice][j], j = 0..127
    const int tid = threadIdx.x;
    const int r0 = blockIdx.x * 64;
    const int h  = blockIdx.y;
    #pragma unroll
    for (int i = 0; i < 4; ++i) {               // A: 64 rows x 64 d, once
        int idx = i*256 + tid;
        int r = idx >> 4, c4 = idx & 15;
        int rg = r0 + r;
        float4 a = make_float4(0.f,0.f,0.f,0.f);
        if (rg < NN) a = *(const float4*)&q[(size_t)rg*128 + h*64 + c4*4];
        As[c4*4+0][r] = a.x; As[c4*4+1][r] = a.y;
        As[c4*4+2][r] = a.z; As[c4*4+3][r] = a.w;
    }
    float acc[4][8] = {};
    const int ty = tid >> 4, tx = tid & 15;
    #pragma unroll 1
    for (int kt = 0; kt < 2; ++kt) {
        __syncthreads();
        #pragma unroll
        for (int i = 0; i < 4; ++i) {           // B^T stage: We[j][h*64+d]
            int idx = i*256 + tid;
            int j = idx >> 3, cq = idx & 7;
            float4 w = *(const float4*)&We[(size_t)j*128 + h*64 + kt*32 + cq*4];
            Bs[cq*4+0][j] = w.x; Bs[cq*4+1][j] = w.y;
            Bs[cq*4+2][j] = w.z; Bs[cq*4+3][j] = w.w;
        }
        __syncthreads();
        #pragma unroll
        for (int kk = 0; kk < 32; ++kk) {
            float4 a  = *(const float4*)&As[kt*32+kk][ty*4];
            float4 b0 = *(const float4*)&Bs[kk][tx*4];
            float4 b1 = *(const float4*)&Bs[kk][64 + tx*4];
            float av[4] = {a.x,a.y,a.z,a.w};
            float bw[8] = {b0.x,b0.y,b0.z,b0.w,b1.x,b1.y,b1.z,b1.w};
            #pragma unroll
            for (int ii = 0; ii < 4; ++ii)
                #pragma unroll
                for (int jj = 0; jj < 8; ++jj)
                    acc[ii][jj] = fmaf(av[ii], bw[jj], acc[ii][jj]);
        }
    }
    #pragma unroll
    for (int ii = 0; ii < 4; ++ii) {
        int r = r0 + ty*4 + ii;
        if (r < NN) {
            *(float4*)&qe[(size_t)r*256 + h*128 + tx*4] =
                make_float4(acc[ii][0],acc[ii][1],acc[ii][2],acc[ii][3]);
            *(float4*)&qe[(size_t)r*256 + h*128 + 64 + tx*4] =
                make_float4(acc[ii][4],acc[ii][5],acc[ii][6],acc[ii][7]);
        }
    }
}

// ---------------------------------------------------------------------------
// Edge pass over DST-SORTED edges (via perm). e_proj is NOT computed per
// edge: logits use the per-node pre-projection qe (q.e_proj == edge_attr.qe),
// and the e_proj part of the aggregation is deferred to k_eagg by
// accumulating w-weighted raw edge_attr per dst (eaggw). Per-edge cost drops
// from a 128x128 GEMM row to two 64-dots + one 128-dot + 3 accumulators.
// ---------------------------------------------------------------------------
__global__ __launch_bounds__(256) void k_edge(
    const int* __restrict__ perm,
    const int* __restrict__ eidx, const int* __restrict__ e_id,
    const float* __restrict__ graph_t, const float* __restrict__ graph_msg,
    const float* __restrict__ Wt, const float* __restrict__ bt,
    const float* __restrict__ lu, const float* __restrict__ q,
    const float* __restrict__ k, const float* __restrict__ v,
    const float* __restrict__ qe,
    float* __restrict__ aggw, float* __restrict__ eaggw,
    float* __restrict__ sden)
{
    __shared__ float EA[64*132];    // edge_attr, e-major, stride 132 (=4 mod 32)
    __shared__ int   srcs[64], dsts[64], eids[64];
    __shared__ float relt[64];
    __shared__ float wl[128];
    const int tid = threadIdx.x;
    const int p0 = blockIdx.x * 64;

    if (tid < 64) {
        int e = perm[p0 + tid];
        int s_ = eidx[e], d_ = eidx[EE + e], id = e_id[e];
        srcs[tid] = s_; dsts[tid] = d_; eids[tid] = id;
        relt[tid] = lu[s_] - graph_t[id];
    }
    __syncthreads();
    // message half (k 64..127): straight e-major float4 copy, loads early
    {
        int e = tid >> 2, c0 = tid & 3;
        const float4* mrow = (const float4*)&graph_msg[(size_t)eids[e]*64];
        float4 m[4];
        #pragma unroll
        for (int i = 0; i < 4; ++i) m[i] = mrow[c0 + i*4];
        #pragma unroll
        for (int i = 0; i < 4; ++i)
            *(float4*)&EA[e*132 + 64 + (c0 + i*4)*4] = m[i];
    }
    // time-encoding half (k 0..63)
    {
        int e = tid >> 2, kq = tid & 3;
        float rt = relt[e];
        #pragma unroll
        for (int it = 0; it < 4; ++it) {
            int k0 = it*16 + kq*4;
            float4 wt = *(const float4*)&Wt[k0];
            float4 bv = *(const float4*)&bt[k0];
            float4 r;
            r.x = cosf(fmaf(rt, wt.x, bv.x));
            r.y = cosf(fmaf(rt, wt.y, bv.y));
            r.z = cosf(fmaf(rt, wt.z, bv.z));
            r.w = cosf(fmaf(rt, wt.w, bv.w));
            *(float4*)&EA[e*132 + k0] = r;
        }
    }
    __syncthreads();
    // logits: 128 threads = 64 edges x 2 heads
    // logit = (q[dst].k[src] + edge_attr.qe[dst]) / 8 ; w = exp(logit)
    if (tid < 128) {
        int e = tid >> 1, h = tid & 1;
        int d_ = dsts[e], s_ = srcs[e];
        const float4* qr  = (const float4*)&q[(size_t)d_*128 + h*64];
        const float4* kr  = (const float4*)&k[(size_t)s_*128 + h*64];
        const float4* qer = (const float4*)&qe[(size_t)d_*256 + (size_t)h*128];
        const float4* ear = (const float4*)&EA[e*132];
        float4 s4 = make_float4(0.f,0.f,0.f,0.f);
        #pragma unroll 8
        for (int i = 0; i < 16; ++i) {
            float4 qv = qr[i], kv = kr[i];
            s4.x = fmaf(qv.x, kv.x, s4.x);
            s4.y = fmaf(qv.y, kv.y, s4.y);
            s4.z = fmaf(qv.z, kv.z, s4.z);
            s4.w = fmaf(qv.w, kv.w, s4.w);
        }
        #pragma unroll 8
        for (int i = 0; i < 32; ++i) {
            float4 ev = ear[i], pv = qer[i];
            s4.x = fmaf(ev.x, pv.x, s4.x);
            s4.y = fmaf(ev.y, pv.y, s4.y);
            s4.z = fmaf(ev.z, pv.z, s4.z);
            s4.w = fmaf(ev.w, pv.w, s4.w);
        }
        float sum = (s4.x + s4.y) + (s4.z + s4.w);
        float w = expf(sum * 0.125f);
        wl[tid] = w;
        atomicAdd(&sden[(size_t)d_*2 + h], w);
    }
    __syncthreads();
    // aggregation: thread (j, g) accumulates over edges g*32..g*32+31:
    //   aggv   col j (d-space, head = j>>6):  sum w * v[src][j]
    //   eaggw  col j (k-space, both heads):   sum w_h * edge_attr[j]
    // flushing one 3-atomic burst per dst-run (edges sorted by dst; e is
    // wave-uniform so the branch doesn't diverge).
    {
        const int j = tid & 127, g = tid >> 7;
        float av = 0.f, ae0 = 0.f, ae1 = 0.f;
        int cur = dsts[g*32];
        #pragma unroll 1
        for (int c = 0; c < 4; ++c) {
            float vv[8];
            #pragma unroll
            for (int i = 0; i < 8; ++i)
                vv[i] = v[(size_t)srcs[g*32 + c*8 + i]*128 + j];
            #pragma unroll
            for (int i = 0; i < 8; ++i) {
                int e = g*32 + c*8 + i;
                int d = dsts[e];
                if (d != cur) {
                    atomicAdd(&aggw[(size_t)cur*128 + j], av);
                    atomicAdd(&eaggw[(size_t)cur*256 + j], ae0);
                    atomicAdd(&eaggw[(size_t)cur*256 + 128 + j], ae1);
                    av = 0.f; ae0 = 0.f; ae1 = 0.f; cur = d;
                }
                float w0 = wl[e*2], w1 = wl[e*2+1];
                float ea = EA[e*132 + j];
                av  = fmaf((j >> 6) ? w1 : w0, vv[i], av);
                ae0 = fmaf(w0, ea, ae0);
                ae1 = fmaf(w1, ea, ae1);
            }
        }
        atomicAdd(&aggw[(size_t)cur*128 + j], av);
        atomicAdd(&eaggw[(size_t)cur*256 + j], ae0);
        atomicAdd(&eaggw[(size_t)cur*256 + 128 + j], ae1);
    }
}

// ---------------------------------------------------------------------------
// deferred e_proj aggregation: aggw[r, h*64+d] += sum_k eaggw[r,h*128+k] *
// We[k, h*64+d].   grid (1563, 2) — blockIdx.y = head
// ---------------------------------------------------------------------------
__global__ __launch_bounds__(256) void k_eagg(
    const float* __restrict__ eaggw, const float* __restrict__ We,
    float* __restrict__ aggw)
{
    __shared__ float As[128][68];   // A^T: [k][row]
    __shared__ float Bs[32][68];
    const int tid = threadIdx.x;
    const int r0 = blockIdx.x * 64;
    const int h  = blockIdx.y;
    #pragma unroll
    for (int i = 0; i < 8; ++i) {               // A: 64 rows x 128 k
        int idx = i*256 + tid;
        int r = idx >> 5, c4 = idx & 31;
        int rg = r0 + r;
        float4 a = make_float4(0.f,0.f,0.f,0.f);
        if (rg < NN) a = *(const float4*)&eaggw[(size_t)rg*256 + (size_t)h*128 + c4*4];
        As[c4*4+0][r] = a.x; As[c4*4+1][r] = a.y;
        As[c4*4+2][r] = a.z; As[c4*4+3][r] = a.w;
    }
    float acc[4][4] = {};
    const int ty = tid >> 4, tx = tid & 15;
    #pragma unroll 1
    for (int kt = 0; kt < 4; ++kt) {
        __syncthreads();
        #pragma unroll
        for (int i = 0; i < 2; ++i) {           // B: 32 k x 64 cols
            int idx = i*256 + tid;
            int kk = idx >> 4, c4 = idx & 15;
            *(float4*)&Bs[kk][c4*4] =
                *(const float4*)&We[(size_t)(kt*32+kk)*128 + h*64 + c4*4];
        }
        __syncthreads();
        #pragma unroll
        for (int kk = 0; kk < 32; ++kk) {
            float4 a = *(const float4*)&As[kt*32+kk][ty*4];
            float4 b = *(const float4*)&Bs[kk][tx*4];
            float av[4] = {a.x,a.y,a.z,a.w};
            float bw[4] = {b.x,b.y,b.z,b.w};
            #pragma unroll
            for (int ii = 0; ii < 4; ++ii)
                #pragma unroll
                for (int jj = 0; jj < 4; ++jj)
                    acc[ii][jj] = fmaf(av[ii], bw[jj], acc[ii][jj]);
        }
    }
    #pragma unroll
    for (int ii = 0; ii < 4; ++ii) {
        int r = r0 + ty*4 + ii;
        if (r < NN) {
            float4* p = (float4*)&aggw[(size_t)r*128 + h*64 + tx*4];
            float4 o = *p;
            o.x += acc[ii][0]; o.y += acc[ii][1];
            o.z += acc[ii][2]; o.w += acc[ii][3];
            *p = o;
        }
    }
}

// ---------------------------------------------------------------------------
// hpre = (aggw/(sden+1e-16) + skip) @ W1 + b1      grid (1563, 2)
// ---------------------------------------------------------------------------
__global__ __launch_bounds__(256) void k_zh(
    const float* __restrict__ aggw, const float* __restrict__ sden,
    const float* __restrict__ skip,
    const float* __restrict__ W1, const float* __restrict__ b1,
    float* __restrict__ hpre)
{
    __shared__ float As[32][68];
    __shared__ float Bs[32][68];
    const int tid = threadIdx.x;
    const int r0 = blockIdx.x * 64;
    const int coloff = blockIdx.y * 64;
    float acc[4][4] = {};
    const int ty = tid >> 4, tx = tid & 15;
    for (int kt = 0; kt < 4; ++kt) {
        const int hsel = kt >> 1;
        #pragma unroll
        for (int i = 0; i < 2; ++i) {
            int idx = i*256 + tid;
            int r = idx >> 3, c4 = idx & 7;
            int rg = r0 + r;
            float4 z = make_float4(0.f,0.f,0.f,0.f);
            if (rg < NN) {
                float4 aw = *(const float4*)&aggw[(size_t)rg*128 + kt*32 + c4*4];
                float4 sk = *(const float4*)&skip[(size_t)rg*128 + kt*32 + c4*4];
                float inv = 1.f / (sden[(size_t)rg*2 + hsel] + 1e-16f);
                z = make_float4(fmaf(aw.x,inv,sk.x), fmaf(aw.y,inv,sk.y),
                                fmaf(aw.z,inv,sk.z), fmaf(aw.w,inv,sk.w));
            }
            As[c4*4+0][r] = z.x; As[c4*4+1][r] = z.y;
            As[c4*4+2][r] = z.z; As[c4*4+3][r] = z.w;
        }
        #pragma unroll
        for (int i = 0; i < 2; ++i) {
            int idx = i*256 + tid;
            int kk = idx >> 4, c4 = idx & 15;
            *(float4*)&Bs[kk][c4*4] =
                *(const float4*)&W1[(size_t)(kt*32+kk)*128 + coloff + c4*4];
        }
        __syncthreads();
        #pragma unroll
        for (int kk = 0; kk < 32; ++kk) {
            float4 a = *(const float4*)&As[kk][ty*4];
            float4 b = *(const float4*)&Bs[kk][tx*4];
            float av[4] = {a.x,a.y,a.z,a.w};
            float bw[4] = {b.x,b.y,b.z,b.w};
            #pragma unroll
            for (int ii = 0; ii < 4; ++ii)
                #pragma unroll
                for (int jj = 0; jj < 4; ++jj)
                    acc[ii][jj] = fmaf(av[ii], bw[jj], acc[ii][jj]);
        }
        __syncthreads();
    }
    float4 bia = *(const float4*)&b1[coloff + tx*4];
    float bw[4] = {bia.x,bia.y,bia.z,bia.w};
    #pragma unroll
    for (int ii = 0; ii < 4; ++ii) {
        int r = r0 + ty*4 + ii;
        if (r < NN) {
            float4 o = make_float4(acc[ii][0]+bw[0], acc[ii][1]+bw[1],
                                   acc[ii][2]+bw[2], acc[ii][3]+bw[3]);
            *(float4*)&hpre[(size_t)r*128 + coloff + tx*4] = o;
        }
    }
}

// ---------------------------------------------------------------------------
// batchnorm stats: per-column sum / sumsq over N rows (block-pre-reduced)
// ---------------------------------------------------------------------------
__global__ __launch_bounds__(256) void k_bnstats(
    const float* __restrict__ hpre, float* __restrict__ bnS, float* __restrict__ bnSQ)
{
    const int tid = threadIdx.x;
    const int col = tid & 127;
    const int half = tid >> 7;
    float s = 0.f, sq = 0.f;
    for (int r = blockIdx.x*2 + half; r < NN; r += gridDim.x*2) {
        float x = hpre[(size_t)r*128 + col];
        s += x; sq = fmaf(x, x, sq);
    }
    __shared__ float ls[256], lq[256];
    ls[tid] = s; lq[tid] = sq;
    __syncthreads();
    if (tid < 128) {
        atomicAdd(&bnS[col],  ls[tid] + ls[tid+128]);
        atomicAdd(&bnSQ[col], lq[tid] + lq[tid+128]);
    }
}

// ---------------------------------------------------------------------------
// z2 = relu(bn(hpre)) @ W2 + b2       grid (1563)
// ---------------------------------------------------------------------------
__global__ __launch_bounds__(256) void k_z2(
    const float* __restrict__ hpre,
    const float* __restrict__ bnS, const float* __restrict__ bnSQ,
    const float* __restrict__ gamma, const float* __restrict__ beta,
    const float* __restrict__ W2, const float* __restrict__ b2,
    float* __restrict__ z2)
{
    __shared__ float As[32][68];
    __shared__ float Bs[32][68];
    __shared__ float scl[128], sft[128];
    const int tid = threadIdx.x;
    const int r0 = blockIdx.x * 64;
    if (tid < 128) {
        float mu  = bnS[tid]  * (1.f/NN);
        float var = bnSQ[tid] * (1.f/NN) - mu*mu;
        float sc  = rsqrtf(var + 1e-5f) * gamma[tid];
        scl[tid] = sc;
        sft[tid] = fmaf(-mu, sc, beta[tid]);
    }
    __syncthreads();
    float acc[4][4] = {};
    const int ty = tid >> 4, tx = tid & 15;
    for (int kt = 0; kt < 4; ++kt) {
        #pragma unroll
        for (int i = 0; i < 2; ++i) {
            int idx = i*256 + tid;
            int r = idx >> 3, c4 = idx & 7;
            int rg = r0 + r;
            int kc = kt*32 + c4*4;
            float4 z = make_float4(0.f,0.f,0.f,0.f);
            if (rg < NN) {
                float4 hv = *(const float4*)&hpre[(size_t)rg*128 + kc];
                z.x = fmaxf(fmaf(hv.x, scl[kc+0], sft[kc+0]), 0.f);
                z.y = fmaxf(fmaf(hv.y, scl[kc+1], sft[kc+1]), 0.f);
                z.z = fmaxf(fmaf(hv.z, scl[kc+2], sft[kc+2]), 0.f);
                z.w = fmaxf(fmaf(hv.w, scl[kc+3], sft[kc+3]), 0.f);
            }
            As[c4*4+0][r] = z.x; As[c4*4+1][r] = z.y;
            As[c4*4+2][r] = z.z; As[c4*4+3][r] = z.w;
        }
        #pragma unroll
        for (int i = 0; i < 2; ++i) {
            int idx = i*256 + tid;
            int kk = idx >> 4, c4 = idx & 15;
            *(float4*)&Bs[kk][c4*4] =
                *(const float4*)&W2[(size_t)(kt*32+kk)*64 + c4*4];
        }
        __syncthreads();
        #pragma unroll
        for (int kk = 0; kk < 32; ++kk) {
            float4 a = *(const float4*)&As[kk][ty*4];
            float4 b = *(const float4*)&Bs[kk][tx*4];
            float av[4] = {a.x,a.y,a.z,a.w};
            float bw[4] = {b.x,b.y,b.z,b.w};
            #pragma unroll
            for (int ii = 0; ii < 4; ++ii)
                #pragma unroll
                for (int jj = 0; jj < 4; ++jj)
                    acc[ii][jj] = fmaf(av[ii], bw[jj], acc[ii][jj]);
        }
        __syncthreads();
    }
    float4 bia = *(const float4*)&b2[tx*4];
    float bw[4] = {bia.x,bia.y,bia.z,bia.w};
    #pragma unroll
    for (int ii = 0; ii < 4; ++ii) {
        int r = r0 + ty*4 + ii;
        if (r < NN) {
            float4 o = make_float4(acc[ii][0]+bw[0], acc[ii][1]+bw[1],
                                   acc[ii][2]+bw[2], acc[ii][3]+bw[3]);
            *(float4*)&z2[(size_t)r*64 + tx*4] = o;
        }
    }
}

// ---------------------------------------------------------------------------
// link prediction: one wave per (pair, which)
// ---------------------------------------------------------------------------
__global__ __launch_bounds__(256) void k_link(
    const float* __restrict__ z2,
    const int* __restrict__ src_idx, const int* __restrict__ dst_idx,
    const int* __restrict__ neg_idx,
    const float* __restrict__ Wls, const float* __restrict__ bls,
    const float* __restrict__ Wld, const float* __restrict__ bld,
    const float* __restrict__ Wlf, const float* __restrict__ blf,
    float* __restrict__ out)
{
    int wid  = blockIdx.x*4 + (threadIdx.x >> 6);
    int lane = threadIdx.x & 63;
    int which = wid / BB;
    int b = wid - which*BB;
    int ia = src_idx[b];
    int ib = which ? neg_idx[b] : dst_idx[b];
    float a = z2[(size_t)ia*64 + lane];
    float c = z2[(size_t)ib*64 + lane];
    float acc = bls[lane] + bld[lane];
    #pragma unroll 8
    for (int k2 = 0; k2 < 64; ++k2) {
        float ak = __shfl(a, k2);
        float ck = __shfl(c, k2);
        acc = fmaf(ak, Wls[k2*64 + lane], acc);
        acc = fmaf(ck, Wld[k2*64 + lane], acc);
    }
    float hj = fmaxf(acc, 0.f) * Wlf[lane];
    #pragma unroll
    for (int off = 32; off > 0; off >>= 1)
        hj += __shfl_down(hj, off);
    if (lane == 0) out[which*BB + b] = hj + blf[0];
}

// ---------------------------------------------------------------------------
extern "C" void kernel_launch(void* const* d_in, const int* in_sizes, int n_in,
                              void* d_out, int out_size, void* d_ws, size_t ws_size,
                              hipStream_t stream)
{
    (void)in_sizes; (void)n_in; (void)out_size; (void)ws_size;
    const float* memt = (const float*)d_in[0];
    const float* lut  = (const float*)d_in[1];
    const float* gt   = (const float*)d_in[2];
    const float* gmsg = (const float*)d_in[3];
    const float* Wt   = (const float*)d_in[4];
    const float* bt   = (const float*)d_in[5];
    const float* Wq   = (const float*)d_in[6];
    const float* bq   = (const float*)d_in[7];
    const float* Wk   = (const float*)d_in[8];
    const float* bk   = (const float*)d_in[9];
    const float* Wv   = (const float*)d_in[10];
    const float* bv   = (const float*)d_in[11];
    const float* We   = (const float*)d_in[12];
    const float* Wsk  = (const float*)d_in[13];
    const float* bsk  = (const float*)d_in[14];
    const float* W1   = (const float*)d_in[15];
    const float* b1   = (const float*)d_in[16];
    const float* gam  = (const float*)d_in[17];
    const float* bet  = (const float*)d_in[18];
    const float* W2   = (const float*)d_in[19];
    const float* b2   = (const float*)d_in[20];
    const float* Wls  = (const float*)d_in[21];
    const float* bls  = (const float*)d_in[22];
    const float* Wld  = (const float*)d_in[23];
    const float* bld  = (const float*)d_in[24];
    const float* Wlf  = (const float*)d_in[25];
    const float* blf  = (const float*)d_in[26];
    const int* n_id   = (const int*)d_in[27];
    const int* eidx   = (const int*)d_in[28];
    const int* e_id   = (const int*)d_in[29];
    const int* sidx   = (const int*)d_in[30];
    const int* didx   = (const int*)d_in[31];
    const int* nidx   = (const int*)d_in[32];

    float* ws = (float*)d_ws;
    float* q    = ws;                 // 12.8M   (reused as hpre)
    float* k    = ws + 12800000;      // 12.8M   (reused as z2)
    float* v    = ws + 25600000;      // 12.8M
    float* skip = ws + 38400000;      // 12.8M
    float* lu   = ws + 51200000;      // 100000
    float* aggw = ws + 51300000;      // 12.8M  (atomic accum, v-part + eagg)
    float* sden = ws + 64100000;      // 200000 (atomic accum)
    float* bnS  = ws + 64300000;      // 128
    float* bnSQ = ws + 64300128;      // 128
    int*   bins = (int*)(ws + 64300256);   // 100352 (cursor after scan)
    int*   csum = (int*)(ws + 64400608);   // 128
    int*   cbase= (int*)(ws + 64400736);   // 128
    int*   perm = (int*)(ws + 64400864);   // 1,000,000
    float* qe   = ws + 65400864;      // 25.6M  (per-node We-projected q)
    float* eaggw= ws + 91000864;      // 25.6M  (atomic accum, w-weighted edge_attr)
    float* hpre = q;                  // alias: q dead after k_edge
    float* z2   = k;                  // alias: k dead after k_edge

    // zero aggw + sden + bnS/bnSQ + bins (contiguous), plus eaggw
    hipMemsetAsync(aggw, 0, (size_t)(12800000 + 200000 + 256 + 100352) * 4, stream);
    hipMemsetAsync(eaggw, 0, (size_t)25600000 * 4, stream);

    dim3 blk(256);
    // counting-sort edges by dst
    k_hist   <<<dim3(3907), blk, 0, stream>>>(eidx, bins);
    k_csum   <<<dim3(NCH),  blk, 0, stream>>>(bins, csum);
    k_cscan  <<<dim3(1), dim3(128), 0, stream>>>(csum, cbase);
    k_bscan  <<<dim3(NCH),  blk, 0, stream>>>(bins, cbase);
    k_scatter<<<dim3(3907), blk, 0, stream>>>(eidx, bins, perm);
    // main pipeline
    k_node<<<dim3(1563), blk, 0, stream>>>(memt, lut, n_id, Wq, bq, Wk, bk,
                                           Wv, bv, Wsk, bsk, q, k, v, skip, lu);
    k_qe<<<dim3(1563, 2), blk, 0, stream>>>(q, We, qe);
    k_edge<<<dim3(15625), blk, 0, stream>>>(perm, eidx, e_id, gt, gmsg, Wt, bt,
                                            lu, q, k, v, qe, aggw, eaggw, sden);
    k_eagg<<<dim3(1563, 2), blk, 0, stream>>>(eaggw, We, aggw);
    k_zh<<<dim3(1563, 2), blk, 0, stream>>>(aggw, sden, skip, W1, b1, hpre);
    k_bnstats<<<dim3(512), blk, 0, stream>>>(hpre, bnS, bnSQ);
    k_z2<<<dim3(1563), blk, 0, stream>>>(hpre, bnS, bnSQ, gam, bet, W2, b2, z2);
    k_link<<<dim3(10000), blk, 0, stream>>>(z2, sidx, didx, nidx,
                                            Wls, bls, Wld, bld, Wlf, blf,
                                            (float*)d_out);
}